// Round 4
// baseline (217.837 us; speedup 1.0000x reference)
//
#include <hip/hip_runtime.h>
#include <math.h>

#define D 1024
#define NROWS 16384
#define NBUF 512

// ws layout (float indices)
#define OFF_MEAN 0      // 1024 floats: column sums of y1 (k_mean atomics)
#define OFF_KEY  1024   // unsigned long long at byte 4096
#define OFF_GATE 2048   // 16384 floats
#define OFF_PART 20480  // NP x 1024 floats of per-block partials
#define ZERO_BYTES 4112 // covers MEAN + KEY

typedef float nfloat4 __attribute__((ext_vector_type(4)));

__device__ __forceinline__ float4 ld4(const float* p) { return *(const float4*)p; }
__device__ __forceinline__ void st4_nt(float* p, float4 v) {
    nfloat4 nv = { v.x, v.y, v.z, v.w };
    __builtin_nontemporal_store(nv, (nfloat4*)p);
}

__device__ __forceinline__ float wave_red(float v) {
    #pragma unroll
    for (int off = 32; off > 0; off >>= 1) v += __shfl_xor(v, off, 64);
    return v;
}

__device__ __forceinline__ float gelu_f(float x) {
    float u = 0.7978845608028654f * (x + 0.044715f * x * x * x);
    float e = __expf(2.0f * u);
    float t = 1.0f - 2.0f / (e + 1.0f);
    return 0.5f * x * (1.0f + t);
}

__device__ __forceinline__ float4 inv_std4(float4 m, float4 m2) {
    float4 r;
    r.x = 1.0f / (sqrtf(fmaxf(m2.x - m.x * m.x, 0.f)) + 1e-5f);
    r.y = 1.0f / (sqrtf(fmaxf(m2.y - m.y * m.y, 0.f)) + 1e-5f);
    r.z = 1.0f / (sqrtf(fmaxf(m2.z - m.z * m.z, 0.f)) + 1e-5f);
    r.w = 1.0f / (sqrtf(fmaxf(m2.w - m.w * m.w, 0.f)) + 1e-5f);
    return r;
}

// ---------------- K1: pass A — gate per row + per-block column partials -------
// grid NP x 256; RPW rows per wave; NON-atomic partial store per block.
template<int RPW>
__global__ __launch_bounds__(256, 4) void k_passA(const float* __restrict__ x,
                                                  const float* __restrict__ ema_x,
                                                  const float* __restrict__ ema_x2,
                                                  const float* __restrict__ ema_y,
                                                  const float* __restrict__ ema_y2,
                                                  const float* __restrict__ lti,
                                                  const float* __restrict__ lto,
                                                  const float* __restrict__ lai,
                                                  const float* __restrict__ lao,
                                                  float* __restrict__ ws) {
    __shared__ float s_acc[D];
    const int tid = threadIdx.x;
    const int wave = tid >> 6, lane = tid & 63;
    for (int i = tid; i < D; i += 256) s_acc[i] = 0.0f;
    __syncthreads();

    const float tau_in = __expf(lti[0]), tau_out = __expf(lto[0]);
    const float a_in  = 1.0f / (1.0f + __expf(-lai[0]));
    const float a_out = 1.0f / (1.0f + __expf(-lao[0]));

    int col[4];
    float4 emx[4], isx[4], emy[4], isy[4];
    #pragma unroll
    for (int j = 0; j < 4; ++j) {
        col[j] = 4 * lane + 256 * j;
        emx[j] = ld4(&ema_x[col[j]]);
        isx[j] = inv_std4(emx[j], ld4(&ema_x2[col[j]]));
        emy[j] = ld4(&ema_y[col[j]]);
        isy[j] = inv_std4(emy[j], ld4(&ema_y2[col[j]]));
    }
    float4 acc[4];
    #pragma unroll
    for (int j = 0; j < 4; ++j) acc[j] = make_float4(0.f, 0.f, 0.f, 0.f);

    const int r0 = (blockIdx.x * 4 + wave) * RPW;
    for (int r = r0; r < r0 + RPW; ++r) {
        const float* xr = x + (size_t)r * D;
        float4 yv[4];
        float zin = 0.f, zout = 0.f;
        #pragma unroll
        for (int j = 0; j < 4; ++j) {
            float4 xv = ld4(&xr[col[j]]);
            float dx, dy;
            dx = (xv.x - emx[j].x) * isx[j].x; zin += dx * dx;
            dx = (xv.y - emx[j].y) * isx[j].y; zin += dx * dx;
            dx = (xv.z - emx[j].z) * isx[j].z; zin += dx * dx;
            dx = (xv.w - emx[j].w) * isx[j].w; zin += dx * dx;
            yv[j].x = gelu_f(xv.x); dy = (yv[j].x - emy[j].x) * isy[j].x; zout += dy * dy;
            yv[j].y = gelu_f(xv.y); dy = (yv[j].y - emy[j].y) * isy[j].y; zout += dy * dy;
            yv[j].z = gelu_f(xv.z); dy = (yv[j].z - emy[j].z) * isy[j].z; zout += dy * dy;
            yv[j].w = gelu_f(xv.w); dy = (yv[j].w - emy[j].w) * isy[j].w; zout += dy * dy;
        }
        zin  = wave_red(zin)  * (1.0f / D);
        zout = wave_red(zout) * (1.0f / D);
        float g = ((1.0f - a_in)  + a_in  * __expf(-tau_in  * zin)) *
                  ((1.0f - a_out) + a_out * __expf(-tau_out * zout));
        if (lane == 0) ws[OFF_GATE + r] = g;
        #pragma unroll
        for (int j = 0; j < 4; ++j) {
            acc[j].x += yv[j].x * g;
            acc[j].y += yv[j].y * g;
            acc[j].z += yv[j].z * g;
            acc[j].w += yv[j].w * g;
        }
    }
    #pragma unroll
    for (int j = 0; j < 4; ++j) {
        atomicAdd(&s_acc[col[j] + 0], acc[j].x);
        atomicAdd(&s_acc[col[j] + 1], acc[j].y);
        atomicAdd(&s_acc[col[j] + 2], acc[j].z);
        atomicAdd(&s_acc[col[j] + 3], acc[j].w);
    }
    __syncthreads();
    // coalesced, non-atomic 4 KB partial store per block
    float4 pv = *(float4*)&s_acc[tid * 4];
    *(float4*)&ws[OFF_PART + (size_t)blockIdx.x * D + tid * 4] = pv;
}

// ---------------- K2: reduce partials -> column sums (low-contention atomics) -
// grid NP/16 x 256; each block sums 16 partial rows, 4 atomics/thread at end.
__global__ __launch_bounds__(256) void k_mean(float* __restrict__ ws) {
    const int tid = threadIdx.x;
    const float* P = &ws[OFF_PART + (size_t)blockIdx.x * 16 * D];
    float4 s = make_float4(0.f, 0.f, 0.f, 0.f);
    #pragma unroll
    for (int i = 0; i < 16; ++i) {
        float4 v = ld4(&P[(size_t)i * D + 4 * tid]);
        s.x += v.x; s.y += v.y; s.z += v.z; s.w += v.w;
    }
    atomicAdd(&ws[OFF_MEAN + 4 * tid + 0], s.x);
    atomicAdd(&ws[OFF_MEAN + 4 * tid + 1], s.y);
    atomicAdd(&ws[OFF_MEAN + 4 * tid + 2], s.z);
    atomicAdd(&ws[OFF_MEAN + 4 * tid + 3], s.w);
}

// ---------------- K3: sims over buf + argmax via atomicMax key ----------------
// ws[OFF_MEAN] holds SUM of y1 columns; 1/NROWS cancels in normalization.
__global__ __launch_bounds__(256) void k_sims(const float* __restrict__ buf,
                                              const unsigned char* __restrict__ mask,
                                              float* __restrict__ ws) {
    __shared__ float s_red[4];
    __shared__ float s_inv;
    const int tid = threadIdx.x, wave = tid >> 6, lane = tid & 63;

    float4 mv = ld4(&ws[OFF_MEAN + tid * 4]);
    float ns = mv.x * mv.x + mv.y * mv.y + mv.z * mv.z + mv.w * mv.w;
    ns = wave_red(ns);
    if (lane == 0) s_red[wave] = ns;
    __syncthreads();
    if (tid == 0) {
        float t = s_red[0] + s_red[1] + s_red[2] + s_red[3];
        s_inv = 1.0f / fmaxf(sqrtf(t), 1e-12f);
    }
    __syncthreads();
    const float inv = s_inv;

    int col[4];
    float4 mvv[4];
    #pragma unroll
    for (int j = 0; j < 4; ++j) {
        col[j] = 4 * lane + 256 * j;
        mvv[j] = ld4(&ws[OFF_MEAN + col[j]]);
    }
    const int n = blockIdx.x * 4 + wave;   // 128 blocks x 4 waves = 512 rows
    const float* br = buf + (size_t)n * D;
    float dot = 0.f, bns = 0.f;
    #pragma unroll
    for (int j = 0; j < 4; ++j) {
        float4 bv = ld4(&br[col[j]]);
        dot += bv.x * mvv[j].x + bv.y * mvv[j].y + bv.z * mvv[j].z + bv.w * mvv[j].w;
        bns += bv.x * bv.x + bv.y * bv.y + bv.z * bv.z + bv.w * bv.w;
    }
    dot = wave_red(dot);
    bns = wave_red(bns);
    if (lane == 0) {
        float sim = -1.0f;
        if (mask[n]) sim = (dot * inv) / fmaxf(sqrtf(bns), 1e-12f);
        unsigned int fb = __float_as_uint(sim);
        unsigned int mono = (fb & 0x80000000u) ? ~fb : (fb | 0x80000000u);
        // ~n in low bits => ties resolve to smallest index (jnp.argmax semantics)
        unsigned long long key = ((unsigned long long)mono << 32) | (unsigned int)(~n);
        atomicMax((unsigned long long*)&ws[OFF_KEY], key);
    }
}

// ---------------- K4: pass B — decode winner inline, project, write out -------
__global__ __launch_bounds__(256, 4) void k_passB(const float* __restrict__ x,
                                                  const float* __restrict__ buf,
                                                  const float* __restrict__ facil,
                                                  const float* __restrict__ lkb,
                                                  const float* __restrict__ lkd,
                                                  const float* __restrict__ ws,
                                                  float* __restrict__ out) {
    __shared__ float s_red[4];
    __shared__ float s_sc[3];   // dampe, coef, valid flag
    const int tid = threadIdx.x, wave = tid >> 6, lane = tid & 63;

    const unsigned long long key = *(const unsigned long long*)&ws[OFF_KEY];
    const int idx = (int)(~(unsigned int)(key & 0xFFFFFFFFull));
    const unsigned int mono = (unsigned int)(key >> 32);
    const unsigned int fb = (mono & 0x80000000u) ? (mono ^ 0x80000000u) : ~mono;
    const float sim = __uint_as_float(fb);

    int col[4];
    float4 vv[4];
    const float* vrow = buf + (size_t)idx * D;
    float bns = 0.f;
    #pragma unroll
    for (int j = 0; j < 4; ++j) {
        col[j] = 4 * lane + 256 * j;
        vv[j] = ld4(&vrow[col[j]]);
        // non-finite components poison bns with NaN -> valid=0
        if (!isfinite(vv[j].x)) bns = __uint_as_float(0x7FC00000u);
        if (!isfinite(vv[j].y)) bns = __uint_as_float(0x7FC00000u);
        if (!isfinite(vv[j].z)) bns = __uint_as_float(0x7FC00000u);
        if (!isfinite(vv[j].w)) bns = __uint_as_float(0x7FC00000u);
        bns += vv[j].x * vv[j].x + vv[j].y * vv[j].y + vv[j].z * vv[j].z + vv[j].w * vv[j].w;
    }
    bns = wave_red(bns);
    if (lane == 0) s_red[wave] = bns;
    __syncthreads();
    if (tid == 0) {
        float t = s_red[0] + s_red[1] + s_red[2] + s_red[3];
        int valid = (t >= 1e-12f) ? 1 : 0;            // NaN compares false
        float sim_val = fminf(fmaxf(sim, 0.0f), 1.0f);
        float fl = facil[idx] * ((sim_val > 0.88f) ? 2.0f : 1.0f);
        float mod = (fl - 1.0f) * sim_val;
        float kb = fminf(fmaxf(__expf(lkb[0]), 0.01f), 4.0f);
        float kd = fminf(fmaxf(__expf(lkd[0]), 0.01f), 0.9f);
        float boost = 1.0f + kb * mod;
        float damp = fmaxf(0.01f, 1.0f - kd * mod);
        s_sc[0] = valid ? damp : 1.0f;
        s_sc[1] = valid ? (boost - damp) : 0.0f;
        s_sc[2] = (float)valid;
    }
    __syncthreads();
    const float dampe = s_sc[0], coef = s_sc[1];
    if (s_sc[2] == 0.0f) {
        #pragma unroll
        for (int j = 0; j < 4; ++j) vv[j] = make_float4(0.f, 0.f, 0.f, 0.f);
    }

    const int r0 = (blockIdx.x * 4 + wave) * 2;   // grid 2048, 2 rows/wave
    for (int r = r0; r < r0 + 2; ++r) {
        const float* xr = x + (size_t)r * D;
        const float g = ws[OFF_GATE + r];
        float4 y1[4];
        float proj = 0.f;
        #pragma unroll
        for (int j = 0; j < 4; ++j) {
            float4 xv = ld4(&xr[col[j]]);
            y1[j].x = gelu_f(xv.x) * g; proj += y1[j].x * vv[j].x;
            y1[j].y = gelu_f(xv.y) * g; proj += y1[j].y * vv[j].y;
            y1[j].z = gelu_f(xv.z) * g; proj += y1[j].z * vv[j].z;
            y1[j].w = gelu_f(xv.w) * g; proj += y1[j].w * vv[j].w;
        }
        proj = wave_red(proj);
        const float pc = proj * coef;
        float* orow = out + (size_t)r * D;
        #pragma unroll
        for (int j = 0; j < 4; ++j) {
            float4 o;
            o.x = y1[j].x * dampe + pc * vv[j].x;
            o.y = y1[j].y * dampe + pc * vv[j].y;
            o.z = y1[j].z * dampe + pc * vv[j].z;
            o.w = y1[j].w * dampe + pc * vv[j].w;
            st4_nt(&orow[col[j]], o);
        }
    }
}

extern "C" void kernel_launch(void* const* d_in, const int* in_sizes, int n_in,
                              void* d_out, int out_size, void* d_ws, size_t ws_size,
                              hipStream_t stream) {
    const float* x      = (const float*)d_in[0];
    const float* lti    = (const float*)d_in[1];
    const float* lto    = (const float*)d_in[2];
    const float* lai    = (const float*)d_in[3];
    const float* lao    = (const float*)d_in[4];
    const float* lkb    = (const float*)d_in[5];
    const float* lkd    = (const float*)d_in[6];
    const float* ema_x  = (const float*)d_in[7];
    const float* ema_x2 = (const float*)d_in[8];
    const float* ema_y  = (const float*)d_in[9];
    const float* ema_y2 = (const float*)d_in[10];
    const float* buf    = (const float*)d_in[11];
    const float* facil  = (const float*)d_in[12];
    const unsigned char* mask = (const unsigned char*)d_in[13];
    float* ws  = (float*)d_ws;
    float* out = (float*)d_out;

    // pick partial-row count by available workspace (deterministic per session)
    int NP;
    if      (ws_size >= ((size_t)OFF_PART + 2048u * D) * 4) NP = 2048;
    else if (ws_size >= ((size_t)OFF_PART + 1024u * D) * 4) NP = 1024;
    else                                                    NP = 512;

    (void)hipMemsetAsync(d_ws, 0, ZERO_BYTES, stream);
    if (NP == 2048)
        hipLaunchKernelGGL(k_passA<2>, dim3(2048), dim3(256), 0, stream,
                           x, ema_x, ema_x2, ema_y, ema_y2, lti, lto, lai, lao, ws);
    else if (NP == 1024)
        hipLaunchKernelGGL(k_passA<4>, dim3(1024), dim3(256), 0, stream,
                           x, ema_x, ema_x2, ema_y, ema_y2, lti, lto, lai, lao, ws);
    else
        hipLaunchKernelGGL(k_passA<8>, dim3(512), dim3(256), 0, stream,
                           x, ema_x, ema_x2, ema_y, ema_y2, lti, lto, lai, lao, ws);
    hipLaunchKernelGGL(k_mean,  dim3(NP / 16), dim3(256), 0, stream, ws);
    hipLaunchKernelGGL(k_sims,  dim3(128), dim3(256), 0, stream, buf, mask, ws);
    hipLaunchKernelGGL(k_passB, dim3(2048), dim3(256), 0, stream,
                       x, buf, facil, lkb, lkd, ws, out);
}

// Round 5
// 214.258 us; speedup vs baseline: 1.0167x; 1.0167x over previous
//
#include <hip/hip_runtime.h>
#include <math.h>

#define D 1024
#define NROWS 16384
#define NBUF 512

// ws layout (float indices)
#define OFF_STAT 0      // 4096 floats: ax[1024], bx[1024], ay[1024], by[1024]
#define OFF_AX   0
#define OFF_BX   1024
#define OFF_AY   2048
#define OFF_BY   3072
#define OFF_MEAN 4096   // 1024 floats: column sums of y1
#define OFF_KEY  5120   // unsigned long long at byte 20480 (8-aligned)
#define OFF_CONST 5124  // tau_in, tau_out, a_in, a_out
#define OFF_GATE 5632   // 16384 floats
#define OFF_PART 22016  // NP x 1024 floats (byte 88064, 16-aligned)

typedef float nfloat4 __attribute__((ext_vector_type(4)));

__device__ __forceinline__ float4 ld4(const float* p) { return *(const float4*)p; }

__device__ __forceinline__ float wave_red(float v) {
    #pragma unroll
    for (int off = 32; off > 0; off >>= 1) v += __shfl_xor(v, off, 64);
    return v;
}

// gelu(x) = 0.5x(1+tanh(u)) with tanh(u)=1-2/(e+1), e=exp(2u)  ==>  x*(1-rcp(e+1))
__device__ __forceinline__ float gelu_f(float x) {
    float x2 = x * x;
    float t1 = fmaf(0.044715f, x2, 1.0f);
    float u2 = (1.5957691216057308f * x) * t1;      // 2*0.79788456*x*(1+0.044715x^2)
    float e  = __expf(u2);
    float r  = __builtin_amdgcn_rcpf(e + 1.0f);     // ~1ulp, plenty for 5e-2 threshold
    return fmaf(-x, r, x);                          // x*(1-r)
}

__device__ __forceinline__ float4 gelu4(float4 x) {
    float4 y;
    y.x = gelu_f(x.x); y.y = gelu_f(x.y); y.z = gelu_f(x.z); y.w = gelu_f(x.w);
    return y;
}

// ---------------- K0: fold stats, constants, zero MEAN/KEY --------------------
__global__ void k_init(const float* __restrict__ ema_x, const float* __restrict__ ema_x2,
                       const float* __restrict__ ema_y, const float* __restrict__ ema_y2,
                       const float* __restrict__ lti, const float* __restrict__ lto,
                       const float* __restrict__ lai, const float* __restrict__ lao,
                       float* __restrict__ ws) {
    int t = threadIdx.x;
    if (t < D) {
        float mx = ema_x[t];
        float vx = fmaxf(ema_x2[t] - mx * mx, 0.0f);
        float ax = 1.0f / (sqrtf(vx) + 1e-5f);
        ws[OFF_AX + t] = ax;
        ws[OFF_BX + t] = mx * ax;
        float my = ema_y[t];
        float vy = fmaxf(ema_y2[t] - my * my, 0.0f);
        float ay = 1.0f / (sqrtf(vy) + 1e-5f);
        ws[OFF_AY + t] = ay;
        ws[OFF_BY + t] = my * ay;
        ws[OFF_MEAN + t] = 0.0f;
    }
    if (t == 0) {
        *(unsigned long long*)&ws[OFF_KEY] = 0ull;
        ws[OFF_CONST + 0] = __expf(lti[0]);
        ws[OFF_CONST + 1] = __expf(lto[0]);
        ws[OFF_CONST + 2] = 1.0f / (1.0f + __expf(-lai[0]));
        ws[OFF_CONST + 3] = 1.0f / (1.0f + __expf(-lao[0]));
    }
}

// ---------------- K1: pass A — gate per row + per-block column partials -------
// Stats live in LDS (ds_read_b128), not registers => no remat/spill.
template<int RPW>
__global__ __launch_bounds__(256, 4) void k_passA(const float* __restrict__ x,
                                                  float* __restrict__ ws) {
    __shared__ float s_stat[4096];   // ax | bx | ay | by
    __shared__ float s_acc[D];
    const int tid = threadIdx.x;
    const int wave = tid >> 6, lane = tid & 63;

    for (int i = tid; i < 1024; i += 256) {
        *(float4*)&s_stat[4 * i] = ld4(&ws[OFF_STAT + 4 * i]);
        s_acc[i] = 0.0f;
    }
    __syncthreads();

    const float tau_in = ws[OFF_CONST + 0], tau_out = ws[OFF_CONST + 1];
    const float a_in  = ws[OFF_CONST + 2], a_out  = ws[OFF_CONST + 3];

    int col[4];
    #pragma unroll
    for (int j = 0; j < 4; ++j) col[j] = 4 * lane + 256 * j;

    float4 acc[4];
    #pragma unroll
    for (int j = 0; j < 4; ++j) acc[j] = make_float4(0.f, 0.f, 0.f, 0.f);

    const int r0 = (blockIdx.x * 4 + wave) * RPW;
    for (int r = r0; r < r0 + RPW; ++r) {
        const float* xr = x + (size_t)r * D;
        float4 xv[4];
        #pragma unroll
        for (int j = 0; j < 4; ++j) xv[j] = ld4(&xr[col[j]]);

        float4 yv[4];
        float zin = 0.f, zout = 0.f;
        #pragma unroll
        for (int j = 0; j < 4; ++j) {
            float4 a = *(const float4*)&s_stat[OFF_AX + col[j]];
            float4 b = *(const float4*)&s_stat[OFF_BX + col[j]];
            float dx;
            dx = fmaf(xv[j].x, a.x, -b.x); zin = fmaf(dx, dx, zin);
            dx = fmaf(xv[j].y, a.y, -b.y); zin = fmaf(dx, dx, zin);
            dx = fmaf(xv[j].z, a.z, -b.z); zin = fmaf(dx, dx, zin);
            dx = fmaf(xv[j].w, a.w, -b.w); zin = fmaf(dx, dx, zin);
            yv[j] = gelu4(xv[j]);
            float4 ay = *(const float4*)&s_stat[OFF_AY + col[j]];
            float4 by = *(const float4*)&s_stat[OFF_BY + col[j]];
            float dy;
            dy = fmaf(yv[j].x, ay.x, -by.x); zout = fmaf(dy, dy, zout);
            dy = fmaf(yv[j].y, ay.y, -by.y); zout = fmaf(dy, dy, zout);
            dy = fmaf(yv[j].z, ay.z, -by.z); zout = fmaf(dy, dy, zout);
            dy = fmaf(yv[j].w, ay.w, -by.w); zout = fmaf(dy, dy, zout);
        }
        zin  = wave_red(zin)  * (1.0f / D);
        zout = wave_red(zout) * (1.0f / D);
        float g = ((1.0f - a_in)  + a_in  * __expf(-tau_in  * zin)) *
                  ((1.0f - a_out) + a_out * __expf(-tau_out * zout));
        if (lane == 0) ws[OFF_GATE + r] = g;
        #pragma unroll
        for (int j = 0; j < 4; ++j) {
            acc[j].x = fmaf(yv[j].x, g, acc[j].x);
            acc[j].y = fmaf(yv[j].y, g, acc[j].y);
            acc[j].z = fmaf(yv[j].z, g, acc[j].z);
            acc[j].w = fmaf(yv[j].w, g, acc[j].w);
        }
    }
    #pragma unroll
    for (int j = 0; j < 4; ++j) {
        atomicAdd(&s_acc[col[j] + 0], acc[j].x);
        atomicAdd(&s_acc[col[j] + 1], acc[j].y);
        atomicAdd(&s_acc[col[j] + 2], acc[j].z);
        atomicAdd(&s_acc[col[j] + 3], acc[j].w);
    }
    __syncthreads();
    *(float4*)&ws[OFF_PART + (size_t)blockIdx.x * D + 4 * tid] = *(float4*)&s_acc[4 * tid];
}

// ---------------- K2: reduce partials -> column sums --------------------------
__global__ __launch_bounds__(256) void k_mean(float* __restrict__ ws) {
    const int tid = threadIdx.x;
    const float* P = &ws[OFF_PART + (size_t)blockIdx.x * 16 * D];
    float4 s = make_float4(0.f, 0.f, 0.f, 0.f);
    #pragma unroll
    for (int i = 0; i < 16; ++i) {
        float4 v = ld4(&P[(size_t)i * D + 4 * tid]);
        s.x += v.x; s.y += v.y; s.z += v.z; s.w += v.w;
    }
    atomicAdd(&ws[OFF_MEAN + 4 * tid + 0], s.x);
    atomicAdd(&ws[OFF_MEAN + 4 * tid + 1], s.y);
    atomicAdd(&ws[OFF_MEAN + 4 * tid + 2], s.z);
    atomicAdd(&ws[OFF_MEAN + 4 * tid + 3], s.w);
}

// ---------------- K3: sims over buf + argmax via atomicMax key ----------------
__global__ __launch_bounds__(256) void k_sims(const float* __restrict__ buf,
                                              const unsigned char* __restrict__ mask,
                                              float* __restrict__ ws) {
    __shared__ float s_red[4];
    __shared__ float s_inv;
    const int tid = threadIdx.x, wave = tid >> 6, lane = tid & 63;

    float4 mv = ld4(&ws[OFF_MEAN + tid * 4]);
    float ns = mv.x * mv.x + mv.y * mv.y + mv.z * mv.z + mv.w * mv.w;
    ns = wave_red(ns);
    if (lane == 0) s_red[wave] = ns;
    __syncthreads();
    if (tid == 0) {
        float t = s_red[0] + s_red[1] + s_red[2] + s_red[3];
        s_inv = 1.0f / fmaxf(sqrtf(t), 1e-12f);
    }
    __syncthreads();
    const float inv = s_inv;

    int col[4];
    float4 mvv[4];
    #pragma unroll
    for (int j = 0; j < 4; ++j) {
        col[j] = 4 * lane + 256 * j;
        mvv[j] = ld4(&ws[OFF_MEAN + col[j]]);
    }
    const int n = blockIdx.x * 4 + wave;   // 128 blocks x 4 waves = 512 rows
    const float* br = buf + (size_t)n * D;
    float dot = 0.f, bns = 0.f;
    #pragma unroll
    for (int j = 0; j < 4; ++j) {
        float4 bv = ld4(&br[col[j]]);
        dot += bv.x * mvv[j].x + bv.y * mvv[j].y + bv.z * mvv[j].z + bv.w * mvv[j].w;
        bns += bv.x * bv.x + bv.y * bv.y + bv.z * bv.z + bv.w * bv.w;
    }
    dot = wave_red(dot);
    bns = wave_red(bns);
    if (lane == 0) {
        float sim = -1.0f;
        if (mask[n]) sim = (dot * inv) / fmaxf(sqrtf(bns), 1e-12f);
        unsigned int fb = __float_as_uint(sim);
        unsigned int mono = (fb & 0x80000000u) ? ~fb : (fb | 0x80000000u);
        unsigned long long key = ((unsigned long long)mono << 32) | (unsigned int)(~n);
        atomicMax((unsigned long long*)&ws[OFF_KEY], key);
    }
}

// ---------------- K4: pass B — decode winner, project, write out --------------
__global__ __launch_bounds__(256, 4) void k_passB(const float* __restrict__ x,
                                                  const float* __restrict__ buf,
                                                  const float* __restrict__ facil,
                                                  const float* __restrict__ lkb,
                                                  const float* __restrict__ lkd,
                                                  const float* __restrict__ ws,
                                                  float* __restrict__ out) {
    __shared__ float s_v[D];
    __shared__ float s_red[4];
    __shared__ float s_sc[3];   // dampe, coef, valid
    const int tid = threadIdx.x, wave = tid >> 6, lane = tid & 63;

    const unsigned long long key = *(const unsigned long long*)&ws[OFF_KEY];
    const int idx = (int)(~(unsigned int)(key & 0xFFFFFFFFull));
    const unsigned int mono = (unsigned int)(key >> 32);
    const unsigned int fb = (mono & 0x80000000u) ? (mono ^ 0x80000000u) : ~mono;
    const float sim = __uint_as_float(fb);

    float4 vt = ld4(&buf[(size_t)idx * D + 4 * tid]);
    float bns = 0.f;
    if (!isfinite(vt.x) || !isfinite(vt.y) || !isfinite(vt.z) || !isfinite(vt.w))
        bns = __uint_as_float(0x7FC00000u);   // NaN poison -> valid=0
    bns += vt.x * vt.x + vt.y * vt.y + vt.z * vt.z + vt.w * vt.w;
    bns = wave_red(bns);
    if (lane == 0) s_red[wave] = bns;
    __syncthreads();
    if (tid == 0) {
        float t = s_red[0] + s_red[1] + s_red[2] + s_red[3];
        int valid = (t >= 1e-12f) ? 1 : 0;    // NaN compares false
        float sim_val = fminf(fmaxf(sim, 0.0f), 1.0f);
        float fl = facil[idx] * ((sim_val > 0.88f) ? 2.0f : 1.0f);
        float mod = (fl - 1.0f) * sim_val;
        float kb = fminf(fmaxf(__expf(lkb[0]), 0.01f), 4.0f);
        float kd = fminf(fmaxf(__expf(lkd[0]), 0.01f), 0.9f);
        float boost = 1.0f + kb * mod;
        float damp = fmaxf(0.01f, 1.0f - kd * mod);
        s_sc[0] = valid ? damp : 1.0f;
        s_sc[1] = valid ? (boost - damp) : 0.0f;
        s_sc[2] = (float)valid;
    }
    __syncthreads();
    const float dampe = s_sc[0], coef = s_sc[1];
    if (s_sc[2] == 0.0f) vt = make_float4(0.f, 0.f, 0.f, 0.f);
    *(float4*)&s_v[4 * tid] = vt;
    __syncthreads();

    int col[4];
    #pragma unroll
    for (int j = 0; j < 4; ++j) col[j] = 4 * lane + 256 * j;

    const int r0 = (blockIdx.x * 4 + wave) * 2;   // 2048 blocks, 2 rows/wave
    for (int r = r0; r < r0 + 2; ++r) {
        const float* xr = x + (size_t)r * D;
        const float g = ws[OFF_GATE + r];
        float4 y1[4], vv[4];
        float proj = 0.f;
        #pragma unroll
        for (int j = 0; j < 4; ++j) {
            float4 xv = ld4(&xr[col[j]]);
            vv[j] = *(const float4*)&s_v[col[j]];
            y1[j] = gelu4(xv);
            y1[j].x *= g; y1[j].y *= g; y1[j].z *= g; y1[j].w *= g;
            proj = fmaf(y1[j].x, vv[j].x, proj);
            proj = fmaf(y1[j].y, vv[j].y, proj);
            proj = fmaf(y1[j].z, vv[j].z, proj);
            proj = fmaf(y1[j].w, vv[j].w, proj);
        }
        proj = wave_red(proj);
        const float pc = proj * coef;
        float* orow = out + (size_t)r * D;
        #pragma unroll
        for (int j = 0; j < 4; ++j) {
            float4 o;
            o.x = fmaf(y1[j].x, dampe, pc * vv[j].x);
            o.y = fmaf(y1[j].y, dampe, pc * vv[j].y);
            o.z = fmaf(y1[j].z, dampe, pc * vv[j].z);
            o.w = fmaf(y1[j].w, dampe, pc * vv[j].w);
            *(float4*)&orow[col[j]] = o;
        }
    }
}

extern "C" void kernel_launch(void* const* d_in, const int* in_sizes, int n_in,
                              void* d_out, int out_size, void* d_ws, size_t ws_size,
                              hipStream_t stream) {
    const float* x      = (const float*)d_in[0];
    const float* lti    = (const float*)d_in[1];
    const float* lto    = (const float*)d_in[2];
    const float* lai    = (const float*)d_in[3];
    const float* lao    = (const float*)d_in[4];
    const float* lkb    = (const float*)d_in[5];
    const float* lkd    = (const float*)d_in[6];
    const float* ema_x  = (const float*)d_in[7];
    const float* ema_x2 = (const float*)d_in[8];
    const float* ema_y  = (const float*)d_in[9];
    const float* ema_y2 = (const float*)d_in[10];
    const float* buf    = (const float*)d_in[11];
    const float* facil  = (const float*)d_in[12];
    const unsigned char* mask = (const unsigned char*)d_in[13];
    float* ws  = (float*)d_ws;
    float* out = (float*)d_out;

    int NP;   // partial rows = passA grid size
    if      (ws_size >= ((size_t)OFF_PART + 2048u * D) * 4) NP = 2048;
    else if (ws_size >= ((size_t)OFF_PART + 1024u * D) * 4) NP = 1024;
    else                                                    NP = 512;

    hipLaunchKernelGGL(k_init, dim3(1), dim3(1024), 0, stream,
                       ema_x, ema_x2, ema_y, ema_y2, lti, lto, lai, lao, ws);
    if (NP == 2048)
        hipLaunchKernelGGL(k_passA<2>, dim3(2048), dim3(256), 0, stream, x, ws);
    else if (NP == 1024)
        hipLaunchKernelGGL(k_passA<4>, dim3(1024), dim3(256), 0, stream, x, ws);
    else
        hipLaunchKernelGGL(k_passA<8>, dim3(512), dim3(256), 0, stream, x, ws);
    hipLaunchKernelGGL(k_mean, dim3(NP / 16), dim3(256), 0, stream, ws);
    hipLaunchKernelGGL(k_sims, dim3(128), dim3(256), 0, stream, buf, mask, ws);
    hipLaunchKernelGGL(k_passB, dim3(2048), dim3(256), 0, stream,
                       x, buf, facil, lkb, lkd, ws, out);
}